// Round 1
// 1757.202 us; speedup vs baseline: 1.8636x; 1.8636x over previous
//
#include <hip/hip_runtime.h>

typedef __bf16 bfrag8 __attribute__((ext_vector_type(8)));
typedef float f32x4 __attribute__((ext_vector_type(4)));
typedef unsigned int u32x4 __attribute__((ext_vector_type(4)));
typedef unsigned short ush;

__device__ __forceinline__ float bf2f(ush s) {
    union { unsigned int u; float f; } un; un.u = ((unsigned int)s) << 16; return un.f;
}
__device__ __forceinline__ ush f2bf(float f) {
    union { float f; unsigned int u; } un; un.f = f;
    unsigned int u = un.u;
    u += 0x7fffu + ((u >> 16) & 1u);   // round-to-nearest-even
    return (ush)(u >> 16);
}

typedef __attribute__((address_space(3))) unsigned int lds_uint;
typedef __attribute__((address_space(1))) const unsigned int glob_uint;

// async 16B/lane global->LDS (dest = wave-uniform base + lane*16)
__device__ __forceinline__ void async_copy16(const ush* g, ush* l) {
    __builtin_amdgcn_global_load_lds((glob_uint*)g, (lds_uint*)l, 16, 0, 0);
}

// ---------------------------------------------------------------------------
// Pre-pass 1: fp32 -> bf16 elementwise (8 elems/thread)
// ---------------------------------------------------------------------------
__global__ __launch_bounds__(256)
void conv_bf(const float* __restrict__ X, ush* __restrict__ Xb, long n8)
{
    long i = (long)blockIdx.x * 256 + threadIdx.x;
    if (i >= n8) return;
    const float4 a = *reinterpret_cast<const float4*>(&X[i * 8]);
    const float4 b = *reinterpret_cast<const float4*>(&X[i * 8 + 4]);
    u32x4 r;
    r[0] = (unsigned int)f2bf(a.x) | ((unsigned int)f2bf(a.y) << 16);
    r[1] = (unsigned int)f2bf(a.z) | ((unsigned int)f2bf(a.w) << 16);
    r[2] = (unsigned int)f2bf(b.x) | ((unsigned int)f2bf(b.y) << 16);
    r[3] = (unsigned int)f2bf(b.z) | ((unsigned int)f2bf(b.w) << 16);
    *reinterpret_cast<u32x4*>(&Xb[i * 8]) = r;
}

// ---------------------------------------------------------------------------
// Pre-pass 2: W (K x N fp32, row-major) -> Wt (N x K bf16, row-major)
// 64x64 tile via LDS, 256 threads.
// ---------------------------------------------------------------------------
__global__ __launch_bounds__(256)
void transpose_bf(const float* __restrict__ W, ush* __restrict__ Wt, int K, int N)
{
    __shared__ __align__(16) ush T[64][72];
    const int tid = threadIdx.x;
    const long kb = (long)blockIdx.y * 64;
    const long nb = (long)blockIdx.x * 64;

    // load 64(k) x 64(n) fp32, store transposed into LDS as bf16
    const int r  = tid >> 4;       // 0..15
    const int c4 = tid & 15;       // col = c4*4
    #pragma unroll
    for (int i = 0; i < 4; ++i) {
        int row = r + i * 16;
        float4 v = *reinterpret_cast<const float4*>(&W[(kb + row) * (long)N + nb + c4 * 4]);
        T[c4 * 4 + 0][row] = f2bf(v.x);
        T[c4 * 4 + 1][row] = f2bf(v.y);
        T[c4 * 4 + 2][row] = f2bf(v.z);
        T[c4 * 4 + 3][row] = f2bf(v.w);
    }
    __syncthreads();

    // write 64(n) x 64(k) bf16, 16B chunks
    const int n  = tid >> 3;       // 0..31
    const int kc = tid & 7;        // col = kc*8
    #pragma unroll
    for (int i = 0; i < 2; ++i) {
        int row = n + i * 32;
        *reinterpret_cast<u32x4*>(&Wt[(nb + row) * (long)K + kb + kc * 8]) =
            *reinterpret_cast<const u32x4*>(&T[row][kc * 8]);
    }
}

// ---------------------------------------------------------------------------
// GEMM (m97 structure): C = A(bf16, MxK) * B^T(bf16, NxK row-major)
// 128x128 block tile, 4 waves (64x64 each), BK=32, mfma_f32_16x16x32_bf16,
// global_load_lds dwordx4 staging, linear LDS.
// ---------------------------------------------------------------------------
#define BM 128
#define BN 128
#define BK 32

__device__ __forceinline__ void store_out(float* p, float v) { *p = v; }
__device__ __forceinline__ void store_out(ush* p, float v)   { *p = f2bf(v); }

template <typename OUT>
__global__ __launch_bounds__(256)
void gemm_bt(const ush* __restrict__ A, const ush* __restrict__ B,
             OUT* __restrict__ C, int M, int N, int K)
{
    __shared__ __align__(16) ush As[BM * BK];
    __shared__ __align__(16) ush Bs[BN * BK];

    const int tid  = threadIdx.x;
    const int wave = tid >> 6, lane = tid & 63;
    const int waveM = wave >> 1, waveN = wave & 1;
    const int lrow = lane & 15, quad = lane >> 4;
    const long m0 = (long)blockIdx.y * BM;
    const long n0 = (long)blockIdx.x * BN;

    // staging geometry: one 1024B chunk = 16 rows x 32 bf16; lane covers
    // row r0 + (lane>>2), cols (lane&3)*8 .. +8   (16B per lane)
    const int srow = lane >> 2;
    const int scol = (lane & 3) * 8;

    const f32x4 fzero = {0.f, 0.f, 0.f, 0.f};
    f32x4 acc[4][4];
    #pragma unroll
    for (int i = 0; i < 4; ++i)
        #pragma unroll
        for (int j = 0; j < 4; ++j) acc[i][j] = fzero;

    for (int k0 = 0; k0 < K; k0 += BK) {
        #pragma unroll
        for (int i = 0; i < 2; ++i) {
            const int r0 = wave * 32 + i * 16;
            async_copy16(&A[(m0 + r0 + srow) * (long)K + k0 + scol], &As[r0 * BK]);
            async_copy16(&B[(n0 + r0 + srow) * (long)K + k0 + scol], &Bs[r0 * BK]);
        }
        __syncthreads();   // compiler emits s_waitcnt vmcnt(0) before s_barrier

        bfrag8 af[4], bf[4];
        #pragma unroll
        for (int mi = 0; mi < 4; ++mi)
            af[mi] = *reinterpret_cast<const bfrag8*>(&As[(waveM * 64 + mi * 16 + lrow) * BK + quad * 8]);
        #pragma unroll
        for (int ni = 0; ni < 4; ++ni)
            bf[ni] = *reinterpret_cast<const bfrag8*>(&Bs[(waveN * 64 + ni * 16 + lrow) * BK + quad * 8]);
        #pragma unroll
        for (int mi = 0; mi < 4; ++mi)
            #pragma unroll
            for (int ni = 0; ni < 4; ++ni)
                acc[mi][ni] = __builtin_amdgcn_mfma_f32_16x16x32_bf16(af[mi], bf[ni], acc[mi][ni], 0, 0, 0);
        __syncthreads();
    }

    #pragma unroll
    for (int mi = 0; mi < 4; ++mi)
        #pragma unroll
        for (int ni = 0; ni < 4; ++ni)
            #pragma unroll
            for (int r = 0; r < 4; ++r) {
                long row = m0 + waveM * 64 + mi * 16 + quad * 4 + r;
                long col = n0 + waveN * 64 + ni * 16 + lrow;
                store_out(&C[row * (long)N + col], acc[mi][ni][r]);
            }
}

// ---------------------------------------------------------------------------
// RoPE in-place on q,k halves of qkv (bf16), fp32 cos/sin tables.
// ---------------------------------------------------------------------------
__global__ void rope_kernel(ush* __restrict__ qkv,
                            const float* __restrict__ cosb, const float* __restrict__ sinb)
{
    int idx = blockIdx.x * 256 + threadIdx.x;  // B*S*H*64 = 8388608
    int i = idx & 63;
    int h = (idx >> 6) & 31;
    int s = (idx >> 11) & 2047;
    int b = idx >> 22;
    float c  = cosb[s * 64 + i];
    float sn = sinb[s * 64 + i];
    long base = ((long)(b * 2048 + s)) * 12288 + h * 128 + 2 * i;
    float qr = bf2f(qkv[base]), qi = bf2f(qkv[base + 1]);
    qkv[base]     = f2bf(qr * c - qi * sn);
    qkv[base + 1] = f2bf(qr * sn + qi * c);
    float kr = bf2f(qkv[base + 4096]), ki = bf2f(qkv[base + 4097]);
    qkv[base + 4096] = f2bf(kr * c - ki * sn);
    qkv[base + 4097] = f2bf(kr * sn + ki * c);
}

// ---------------------------------------------------------------------------
// Flash attention (causal, online softmax), bf16 in/out, fp32 accumulators.
// ---------------------------------------------------------------------------
#define LDK 136
#define LDV 72
#define LDP 72

__global__ __launch_bounds__(256)
void attn_kernel(const ush* __restrict__ qkv, ush* __restrict__ y)
{
    __shared__ ush Ks[64 * LDK];    // [kv][d]
    __shared__ ush Vt[128 * LDV];   // [d][kv]
    __shared__ ush Ps[128 * LDP];   // [q][kv]

    const int qt = blockIdx.x;
    const int bh = blockIdx.y;
    const int b = bh >> 5, h = bh & 31;
    const int tid = threadIdx.x, wave = tid >> 6, lane = tid & 63;
    const int lrow = lane & 15, quad = lane >> 4;
    const int q0 = qt * 128;
    const long rs = 12288;
    const ush* qb = qkv + (long)b * 2048 * rs + h * 128;
    const ush* kb = qb + 4096;
    const ush* vb = qb + 8192;
    const float scale = 0.08838834764831845f;  // 1/sqrt(128)

    bfrag8 qf[2][4];
    #pragma unroll
    for (int mi = 0; mi < 2; ++mi)
        #pragma unroll
        for (int kk = 0; kk < 4; ++kk) {
            long qrow = q0 + wave * 32 + mi * 16 + lrow;
            qf[mi][kk] = *reinterpret_cast<const bfrag8*>(&qb[qrow * rs + kk * 32 + quad * 8]);
        }

    const f32x4 fzero = {0.f, 0.f, 0.f, 0.f};
    f32x4 O[2][8];
    #pragma unroll
    for (int mi = 0; mi < 2; ++mi)
        #pragma unroll
        for (int dt = 0; dt < 8; ++dt) O[mi][dt] = fzero;
    f32x4 mst[2], lst[2];
    #pragma unroll
    for (int mi = 0; mi < 2; ++mi)
        #pragma unroll
        for (int r = 0; r < 4; ++r) { mst[mi][r] = -1e30f; lst[mi][r] = 0.f; }

    const int ntiles = 2 * qt + 2;
    for (int nt = 0; nt < ntiles; ++nt) {
        const int kv0 = nt * 64;
        #pragma unroll
        for (int i = 0; i < 4; ++i) {
            int c = tid + i * 256;
            int row = c >> 4, cc = c & 15;
            u32x4 v = *reinterpret_cast<const u32x4*>(&kb[(long)(kv0 + row) * rs + cc * 8]);
            *reinterpret_cast<u32x4*>(&Ks[row * LDK + cc * 8]) = v;
        }
        #pragma unroll
        for (int i = 0; i < 4; ++i) {
            int c = tid + i * 256;
            int row = c >> 4, cc = c & 15;
            u32x4 v = *reinterpret_cast<const u32x4*>(&vb[(long)(kv0 + row) * rs + cc * 8]);
            const ush* pv = reinterpret_cast<const ush*>(&v);
            #pragma unroll
            for (int j = 0; j < 8; ++j)
                Vt[(cc * 8 + j) * LDV + row] = pv[j];
        }
        __syncthreads();

        f32x4 sv[2][4];
        #pragma unroll
        for (int ni = 0; ni < 4; ++ni) {
            bfrag8 kf[4];
            #pragma unroll
            for (int kk = 0; kk < 4; ++kk)
                kf[kk] = *reinterpret_cast<const bfrag8*>(&Ks[(ni * 16 + lrow) * LDK + kk * 32 + quad * 8]);
            #pragma unroll
            for (int mi = 0; mi < 2; ++mi) {
                f32x4 a = fzero;
                #pragma unroll
                for (int kk = 0; kk < 4; ++kk)
                    a = __builtin_amdgcn_mfma_f32_16x16x32_bf16(qf[mi][kk], kf[kk], a, 0, 0, 0);
                sv[mi][ni] = a;
            }
        }

        #pragma unroll
        for (int mi = 0; mi < 2; ++mi)
            #pragma unroll
            for (int ni = 0; ni < 4; ++ni)
                #pragma unroll
                for (int r = 0; r < 4; ++r) {
                    int q  = q0 + wave * 32 + mi * 16 + quad * 4 + r;
                    int kv = kv0 + ni * 16 + lrow;
                    float x = sv[mi][ni][r] * scale;
                    sv[mi][ni][r] = (kv <= q) ? x : -1e30f;
                }

        #pragma unroll
        for (int mi = 0; mi < 2; ++mi) {
            f32x4 rmax;
            #pragma unroll
            for (int r = 0; r < 4; ++r)
                rmax[r] = fmaxf(fmaxf(sv[mi][0][r], sv[mi][1][r]),
                                fmaxf(sv[mi][2][r], sv[mi][3][r]));
            #pragma unroll
            for (int off = 1; off < 16; off <<= 1)
                #pragma unroll
                for (int r = 0; r < 4; ++r)
                    rmax[r] = fmaxf(rmax[r], __shfl_xor(rmax[r], off, 64));

            f32x4 mnew, alpha;
            #pragma unroll
            for (int r = 0; r < 4; ++r) {
                mnew[r]  = fmaxf(mst[mi][r], rmax[r]);
                alpha[r] = __expf(mst[mi][r] - mnew[r]);
            }
            f32x4 rsum = fzero;
            #pragma unroll
            for (int ni = 0; ni < 4; ++ni)
                #pragma unroll
                for (int r = 0; r < 4; ++r) {
                    float p = __expf(sv[mi][ni][r] - mnew[r]);
                    sv[mi][ni][r] = p;
                    rsum[r] += p;
                }
            #pragma unroll
            for (int off = 1; off < 16; off <<= 1)
                #pragma unroll
                for (int r = 0; r < 4; ++r)
                    rsum[r] += __shfl_xor(rsum[r], off, 64);
            #pragma unroll
            for (int r = 0; r < 4; ++r) {
                lst[mi][r] = lst[mi][r] * alpha[r] + rsum[r];
                mst[mi][r] = mnew[r];
            }
            #pragma unroll
            for (int dt = 0; dt < 8; ++dt)
                #pragma unroll
                for (int r = 0; r < 4; ++r)
                    O[mi][dt][r] *= alpha[r];
            #pragma unroll
            for (int ni = 0; ni < 4; ++ni)
                #pragma unroll
                for (int r = 0; r < 4; ++r)
                    Ps[(wave * 32 + mi * 16 + quad * 4 + r) * LDP + ni * 16 + lrow]
                        = f2bf(sv[mi][ni][r]);
        }

        __syncthreads();

        bfrag8 pf[2][2];
        #pragma unroll
        for (int mi = 0; mi < 2; ++mi)
            #pragma unroll
            for (int nk = 0; nk < 2; ++nk)
                pf[mi][nk] = *reinterpret_cast<const bfrag8*>(
                    &Ps[(wave * 32 + mi * 16 + lrow) * LDP + nk * 32 + quad * 8]);
        #pragma unroll
        for (int dt = 0; dt < 8; ++dt) {
            bfrag8 vf[2];
            #pragma unroll
            for (int nk = 0; nk < 2; ++nk)
                vf[nk] = *reinterpret_cast<const bfrag8*>(
                    &Vt[(dt * 16 + lrow) * LDV + nk * 32 + quad * 8]);
            #pragma unroll
            for (int mi = 0; mi < 2; ++mi)
                #pragma unroll
                for (int nk = 0; nk < 2; ++nk)
                    O[mi][dt] = __builtin_amdgcn_mfma_f32_16x16x32_bf16(pf[mi][nk], vf[nk], O[mi][dt], 0, 0, 0);
        }
        __syncthreads();
    }

    #pragma unroll
    for (int mi = 0; mi < 2; ++mi)
        #pragma unroll
        for (int r = 0; r < 4; ++r) {
            float inv = 1.0f / lst[mi][r];
            long q = q0 + wave * 32 + mi * 16 + quad * 4 + r;
            long base = (long)(b * 2048 + q) * 4096 + h * 128 + lrow;
            #pragma unroll
            for (int dt = 0; dt < 8; ++dt)
                y[base + dt * 16] = f2bf(O[mi][dt][r] * inv);
        }
}

// ---------------------------------------------------------------------------
// Workspace layout (224 MB, with aliasing):
//   [0,          100663296)  qkv  : 4096 x 12288 bf16
//   [100663296,  134217728)  xb   : 4096 x 4096 bf16   -> reused as wpt after GEMM1
//   [134217728,  234881024)  wat  : 12288 x 4096 bf16  -> first 33.5MB reused as y after GEMM1
// ---------------------------------------------------------------------------
extern "C" void kernel_launch(void* const* d_in, const int* in_sizes, int n_in,
                              void* d_out, int out_size, void* d_ws, size_t ws_size,
                              hipStream_t stream)
{
    const float* x  = (const float*)d_in[0];   // (2,2048,4096) fp32
    const float* wa = (const float*)d_in[1];   // (4096,12288) fp32
    const float* wp = (const float*)d_in[2];   // (4096,4096) fp32
    const float* fc = (const float*)d_in[3];   // (2048,64) fp32
    const float* fs = (const float*)d_in[4];   // (2048,64) fp32
    float* out = (float*)d_out;                // (2,2048,4096) fp32

    char* ws = (char*)d_ws;
    ush* qkv = (ush*)ws;                          // 100.7 MB
    ush* xb  = (ush*)(ws + 100663296);            // 33.5 MB (later wpt)
    ush* wat = (ush*)(ws + 134217728);            // 100.7 MB (later y)
    ush* wpt = xb;                                // aliases xb (dead after GEMM1)
    ush* y   = wat;                               // aliases wat (dead after GEMM1)

    // 1. x -> bf16
    conv_bf<<<8192, 256, 0, stream>>>(x, xb, 2097152);
    // 2. w_atten (4096x12288) -> wat (12288x4096 bf16, transposed)
    transpose_bf<<<dim3(12288 / 64, 4096 / 64), 256, 0, stream>>>(wa, wat, 4096, 12288);
    // 3. qkv = x @ w_atten   (bf16 x bf16^T -> bf16)
    gemm_bt<ush><<<dim3(12288 / BN, 4096 / BM), 256, 0, stream>>>(xb, wat, qkv, 4096, 12288, 4096);
    // 4. w_proj -> wpt (4096x4096 bf16, transposed); xb is dead now
    transpose_bf<<<dim3(4096 / 64, 4096 / 64), 256, 0, stream>>>(wp, wpt, 4096, 4096);
    // 5. RoPE in-place on q,k
    rope_kernel<<<8388608 / 256, 256, 0, stream>>>(qkv, fc, fs);
    // 6. causal flash attention -> y (bf16); wat is dead now
    attn_kernel<<<dim3(16, 64), 256, 0, stream>>>(qkv, y);
    // 7. out = y @ w_proj   (bf16 x bf16^T -> fp32)
    gemm_bt<float><<<dim3(4096 / BN, 4096 / BM), 256, 0, stream>>>(y, wpt, out, 4096, 4096, 4096);
}

// Round 2
// 1388.527 us; speedup vs baseline: 2.3584x; 1.2655x over previous
//
#include <hip/hip_runtime.h>

typedef __bf16 bfrag8 __attribute__((ext_vector_type(8)));
typedef float f32x4 __attribute__((ext_vector_type(4)));
typedef unsigned int u32x4 __attribute__((ext_vector_type(4)));
typedef unsigned short ush;

__device__ __forceinline__ float bf2f(ush s) {
    union { unsigned int u; float f; } un; un.u = ((unsigned int)s) << 16; return un.f;
}
__device__ __forceinline__ ush f2bf(float f) {
    union { float f; unsigned int u; } un; un.f = f;
    unsigned int u = un.u;
    u += 0x7fffu + ((u >> 16) & 1u);   // round-to-nearest-even
    return (ush)(u >> 16);
}

typedef __attribute__((address_space(3))) unsigned int lds_uint;
typedef __attribute__((address_space(1))) const unsigned int glob_uint;

// async 16B/lane global->LDS (dest = wave-uniform base + lane*16)
__device__ __forceinline__ void async_copy16(const ush* g, ush* l) {
    __builtin_amdgcn_global_load_lds((glob_uint*)g, (lds_uint*)l, 16, 0, 0);
}

// ---------------------------------------------------------------------------
// Pre-pass 1: fp32 -> bf16 elementwise (8 elems/thread)
// ---------------------------------------------------------------------------
__global__ __launch_bounds__(256)
void conv_bf(const float* __restrict__ X, ush* __restrict__ Xb, long n8)
{
    long i = (long)blockIdx.x * 256 + threadIdx.x;
    if (i >= n8) return;
    const float4 a = *reinterpret_cast<const float4*>(&X[i * 8]);
    const float4 b = *reinterpret_cast<const float4*>(&X[i * 8 + 4]);
    u32x4 r;
    r[0] = (unsigned int)f2bf(a.x) | ((unsigned int)f2bf(a.y) << 16);
    r[1] = (unsigned int)f2bf(a.z) | ((unsigned int)f2bf(a.w) << 16);
    r[2] = (unsigned int)f2bf(b.x) | ((unsigned int)f2bf(b.y) << 16);
    r[3] = (unsigned int)f2bf(b.z) | ((unsigned int)f2bf(b.w) << 16);
    *reinterpret_cast<u32x4*>(&Xb[i * 8]) = r;
}

// ---------------------------------------------------------------------------
// Pre-pass 2: W (K x N fp32, row-major) -> Wt (N x K bf16, row-major)
// ---------------------------------------------------------------------------
__global__ __launch_bounds__(256)
void transpose_bf(const float* __restrict__ W, ush* __restrict__ Wt, int K, int N)
{
    __shared__ __align__(16) ush T[64][72];
    const int tid = threadIdx.x;
    const long kb = (long)blockIdx.y * 64;
    const long nb = (long)blockIdx.x * 64;

    const int r  = tid >> 4;       // 0..15
    const int c4 = tid & 15;       // col = c4*4
    #pragma unroll
    for (int i = 0; i < 4; ++i) {
        int row = r + i * 16;
        float4 v = *reinterpret_cast<const float4*>(&W[(kb + row) * (long)N + nb + c4 * 4]);
        T[c4 * 4 + 0][row] = f2bf(v.x);
        T[c4 * 4 + 1][row] = f2bf(v.y);
        T[c4 * 4 + 2][row] = f2bf(v.z);
        T[c4 * 4 + 3][row] = f2bf(v.w);
    }
    __syncthreads();

    const int n  = tid >> 3;       // 0..31
    const int kc = tid & 7;        // col = kc*8
    #pragma unroll
    for (int i = 0; i < 2; ++i) {
        int row = n + i * 32;
        *reinterpret_cast<u32x4*>(&Wt[(nb + row) * (long)K + kb + kc * 8]) =
            *reinterpret_cast<const u32x4*>(&T[row][kc * 8]);
    }
}

// ---------------------------------------------------------------------------
// Pre-pass 3: V section of qkv (bf16 [b][s][h*128+d]) -> vt (bf16 [b*h][d][s]).
// Per block: one (bh, 64-wide s-tile). LDS [128][64] linear.
// Per-instruction lane mappings chosen so scatter dim is wave-uniform:
//   load:  s = lane (varies), d-chunk uniform -> LDS write bank = lane/2 (free)
//   store: contiguous b128 reads, 8-span uniform (free)
// ---------------------------------------------------------------------------
__global__ __launch_bounds__(256)
void vtrans_kernel(const ush* __restrict__ qkv, ush* __restrict__ vt)
{
    __shared__ __align__(16) ush T[128 * 64];
    const int tid = threadIdx.x;
    const int s0 = blockIdx.x * 64;
    const int bh = blockIdx.y;
    const int b = bh >> 5, h = bh & 31;
    const ush* vbase = qkv + (long)b * 2048 * 12288 + 8192 + h * 128;

    #pragma unroll
    for (int i = 0; i < 4; ++i) {
        int c = tid + i * 256;
        int sl = c & 63, cd = c >> 6;        // cd wave-uniform per instruction
        u32x4 v = *reinterpret_cast<const u32x4*>(&vbase[(long)(s0 + sl) * 12288 + cd * 8]);
        const ush* pv = reinterpret_cast<const ush*>(&v);
        #pragma unroll
        for (int j = 0; j < 8; ++j)
            T[(cd * 8 + j) * 64 + sl] = pv[j];
    }
    __syncthreads();

    #pragma unroll
    for (int i = 0; i < 4; ++i) {
        int c = tid + i * 256;
        int d = c >> 3, sc = c & 7;
        *reinterpret_cast<u32x4*>(&vt[((long)bh * 128 + d) * 2048 + s0 + sc * 8]) =
            *reinterpret_cast<const u32x4*>(&T[d * 64 + sc * 8]);
    }
}

// ---------------------------------------------------------------------------
// GEMM (m97 structure): C = A(bf16, MxK) * B^T(bf16, NxK row-major)
// ---------------------------------------------------------------------------
#define BM 128
#define BN 128
#define BK 32

__device__ __forceinline__ void store_out(float* p, float v) { *p = v; }
__device__ __forceinline__ void store_out(ush* p, float v)   { *p = f2bf(v); }

template <typename OUT>
__global__ __launch_bounds__(256)
void gemm_bt(const ush* __restrict__ A, const ush* __restrict__ B,
             OUT* __restrict__ C, int M, int N, int K)
{
    __shared__ __align__(16) ush As[BM * BK];
    __shared__ __align__(16) ush Bs[BN * BK];

    const int tid  = threadIdx.x;
    const int wave = tid >> 6, lane = tid & 63;
    const int waveM = wave >> 1, waveN = wave & 1;
    const int lrow = lane & 15, quad = lane >> 4;
    const long m0 = (long)blockIdx.y * BM;
    const long n0 = (long)blockIdx.x * BN;

    const int srow = lane >> 2;
    const int scol = (lane & 3) * 8;

    const f32x4 fzero = {0.f, 0.f, 0.f, 0.f};
    f32x4 acc[4][4];
    #pragma unroll
    for (int i = 0; i < 4; ++i)
        #pragma unroll
        for (int j = 0; j < 4; ++j) acc[i][j] = fzero;

    for (int k0 = 0; k0 < K; k0 += BK) {
        #pragma unroll
        for (int i = 0; i < 2; ++i) {
            const int r0 = wave * 32 + i * 16;
            async_copy16(&A[(m0 + r0 + srow) * (long)K + k0 + scol], &As[r0 * BK]);
            async_copy16(&B[(n0 + r0 + srow) * (long)K + k0 + scol], &Bs[r0 * BK]);
        }
        __syncthreads();

        bfrag8 af[4], bf[4];
        #pragma unroll
        for (int mi = 0; mi < 4; ++mi)
            af[mi] = *reinterpret_cast<const bfrag8*>(&As[(waveM * 64 + mi * 16 + lrow) * BK + quad * 8]);
        #pragma unroll
        for (int ni = 0; ni < 4; ++ni)
            bf[ni] = *reinterpret_cast<const bfrag8*>(&Bs[(waveN * 64 + ni * 16 + lrow) * BK + quad * 8]);
        #pragma unroll
        for (int mi = 0; mi < 4; ++mi)
            #pragma unroll
            for (int ni = 0; ni < 4; ++ni)
                acc[mi][ni] = __builtin_amdgcn_mfma_f32_16x16x32_bf16(af[mi], bf[ni], acc[mi][ni], 0, 0, 0);
        __syncthreads();
    }

    #pragma unroll
    for (int mi = 0; mi < 4; ++mi)
        #pragma unroll
        for (int ni = 0; ni < 4; ++ni)
            #pragma unroll
            for (int r = 0; r < 4; ++r) {
                long row = m0 + waveM * 64 + mi * 16 + quad * 4 + r;
                long col = n0 + waveN * 64 + ni * 16 + lrow;
                store_out(&C[row * (long)N + col], acc[mi][ni][r]);
            }
}

// ---------------------------------------------------------------------------
// RoPE in-place on q,k halves of qkv (bf16), fp32 cos/sin tables.
// ---------------------------------------------------------------------------
__global__ void rope_kernel(ush* __restrict__ qkv,
                            const float* __restrict__ cosb, const float* __restrict__ sinb)
{
    int idx = blockIdx.x * 256 + threadIdx.x;  // B*S*H*64 = 8388608
    int i = idx & 63;
    int h = (idx >> 6) & 31;
    int s = (idx >> 11) & 2047;
    int b = idx >> 22;
    float c  = cosb[s * 64 + i];
    float sn = sinb[s * 64 + i];
    long base = ((long)(b * 2048 + s)) * 12288 + h * 128 + 2 * i;
    float qr = bf2f(qkv[base]), qi = bf2f(qkv[base + 1]);
    qkv[base]     = f2bf(qr * c - qi * sn);
    qkv[base + 1] = f2bf(qr * sn + qi * c);
    float kr = bf2f(qkv[base + 4096]), ki = bf2f(qkv[base + 4097]);
    qkv[base + 4096] = f2bf(kr * c - ki * sn);
    qkv[base + 4097] = f2bf(kr * sn + ki * c);
}

// ---------------------------------------------------------------------------
// Flash attention (causal, online softmax), bf16 in/out, fp32 accumulators.
// V comes pre-transposed ([bh][d][s]) -> contiguous b128 staging, no conflicts.
// 2 barriers per KV tile (Ps rows are wave-private; mid-barrier removed).
// Grid: x = bh (64), y -> qt = 15 - y  (longest blocks dispatch first).
// ---------------------------------------------------------------------------
#define LDK 136
#define LDV 72
#define LDP 72

__global__ __launch_bounds__(256)
void attn_kernel(const ush* __restrict__ qkv, const ush* __restrict__ vt,
                 ush* __restrict__ y)
{
    __shared__ ush Ks[64 * LDK];    // [kv][d]
    __shared__ ush Vt[128 * LDV];   // [d][kv]
    __shared__ ush Ps[128 * LDP];   // [q][kv]

    const int bh = blockIdx.x;
    const int qt = 15 - blockIdx.y;
    const int b = bh >> 5, h = bh & 31;
    const int tid = threadIdx.x, wave = tid >> 6, lane = tid & 63;
    const int lrow = lane & 15, quad = lane >> 4;
    const int q0 = qt * 128;
    const long rs = 12288;
    const ush* qb = qkv + (long)b * 2048 * rs + h * 128;
    const ush* kb = qb + 4096;
    const ush* vtb = vt + (long)bh * 128 * 2048;
    const float scale = 0.08838834764831845f;  // 1/sqrt(128)

    bfrag8 qf[2][4];
    #pragma unroll
    for (int mi = 0; mi < 2; ++mi)
        #pragma unroll
        for (int kk = 0; kk < 4; ++kk) {
            long qrow = q0 + wave * 32 + mi * 16 + lrow;
            qf[mi][kk] = *reinterpret_cast<const bfrag8*>(&qb[qrow * rs + kk * 32 + quad * 8]);
        }

    const f32x4 fzero = {0.f, 0.f, 0.f, 0.f};
    f32x4 O[2][8];
    #pragma unroll
    for (int mi = 0; mi < 2; ++mi)
        #pragma unroll
        for (int dt = 0; dt < 8; ++dt) O[mi][dt] = fzero;
    f32x4 mst[2], lst[2];
    #pragma unroll
    for (int mi = 0; mi < 2; ++mi)
        #pragma unroll
        for (int r = 0; r < 4; ++r) { mst[mi][r] = -1e30f; lst[mi][r] = 0.f; }

    const int ntiles = 2 * qt + 2;
    for (int nt = 0; nt < ntiles; ++nt) {
        const int kv0 = nt * 64;
        // K tile: [64 kv][128 d], contiguous 16B chunks
        #pragma unroll
        for (int i = 0; i < 4; ++i) {
            int c = tid + i * 256;
            int row = c >> 4, cc = c & 15;
            u32x4 v = *reinterpret_cast<const u32x4*>(&kb[(long)(kv0 + row) * rs + cc * 8]);
            *reinterpret_cast<u32x4*>(&Ks[row * LDK + cc * 8]) = v;
        }
        // V^T tile: [128 d][64 kv] from pre-transposed vt, contiguous 16B chunks
        #pragma unroll
        for (int i = 0; i < 4; ++i) {
            int c = tid + i * 256;
            int row = c >> 3, cc = c & 7;
            u32x4 v = *reinterpret_cast<const u32x4*>(&vtb[(long)row * 2048 + kv0 + cc * 8]);
            *reinterpret_cast<u32x4*>(&Vt[row * LDV + cc * 8]) = v;
        }
        __syncthreads();

        f32x4 sv[2][4];
        #pragma unroll
        for (int ni = 0; ni < 4; ++ni) {
            bfrag8 kf[4];
            #pragma unroll
            for (int kk = 0; kk < 4; ++kk)
                kf[kk] = *reinterpret_cast<const bfrag8*>(&Ks[(ni * 16 + lrow) * LDK + kk * 32 + quad * 8]);
            #pragma unroll
            for (int mi = 0; mi < 2; ++mi) {
                f32x4 a = fzero;
                #pragma unroll
                for (int kk = 0; kk < 4; ++kk)
                    a = __builtin_amdgcn_mfma_f32_16x16x32_bf16(qf[mi][kk], kf[kk], a, 0, 0, 0);
                sv[mi][ni] = a;
            }
        }

        #pragma unroll
        for (int mi = 0; mi < 2; ++mi)
            #pragma unroll
            for (int ni = 0; ni < 4; ++ni)
                #pragma unroll
                for (int r = 0; r < 4; ++r) {
                    int q  = q0 + wave * 32 + mi * 16 + quad * 4 + r;
                    int kv = kv0 + ni * 16 + lrow;
                    float x = sv[mi][ni][r] * scale;
                    sv[mi][ni][r] = (kv <= q) ? x : -1e30f;
                }

        #pragma unroll
        for (int mi = 0; mi < 2; ++mi) {
            f32x4 rmax;
            #pragma unroll
            for (int r = 0; r < 4; ++r)
                rmax[r] = fmaxf(fmaxf(sv[mi][0][r], sv[mi][1][r]),
                                fmaxf(sv[mi][2][r], sv[mi][3][r]));
            #pragma unroll
            for (int off = 1; off < 16; off <<= 1)
                #pragma unroll
                for (int r = 0; r < 4; ++r)
                    rmax[r] = fmaxf(rmax[r], __shfl_xor(rmax[r], off, 64));

            f32x4 mnew, alpha;
            #pragma unroll
            for (int r = 0; r < 4; ++r) {
                mnew[r]  = fmaxf(mst[mi][r], rmax[r]);
                alpha[r] = __expf(mst[mi][r] - mnew[r]);
            }
            f32x4 rsum = fzero;
            #pragma unroll
            for (int ni = 0; ni < 4; ++ni)
                #pragma unroll
                for (int r = 0; r < 4; ++r) {
                    float p = __expf(sv[mi][ni][r] - mnew[r]);
                    sv[mi][ni][r] = p;
                    rsum[r] += p;
                }
            #pragma unroll
            for (int off = 1; off < 16; off <<= 1)
                #pragma unroll
                for (int r = 0; r < 4; ++r)
                    rsum[r] += __shfl_xor(rsum[r], off, 64);
            #pragma unroll
            for (int r = 0; r < 4; ++r) {
                lst[mi][r] = lst[mi][r] * alpha[r] + rsum[r];
                mst[mi][r] = mnew[r];
            }
            #pragma unroll
            for (int dt = 0; dt < 8; ++dt)
                #pragma unroll
                for (int r = 0; r < 4; ++r)
                    O[mi][dt][r] *= alpha[r];
            #pragma unroll
            for (int ni = 0; ni < 4; ++ni)
                #pragma unroll
                for (int r = 0; r < 4; ++r)
                    Ps[(wave * 32 + mi * 16 + quad * 4 + r) * LDP + ni * 16 + lrow]
                        = f2bf(sv[mi][ni][r]);
        }

        // no barrier: Ps rows are wave-private; compiler orders LDS via lgkmcnt

        bfrag8 pf[2][2];
        #pragma unroll
        for (int mi = 0; mi < 2; ++mi)
            #pragma unroll
            for (int nk = 0; nk < 2; ++nk)
                pf[mi][nk] = *reinterpret_cast<const bfrag8*>(
                    &Ps[(wave * 32 + mi * 16 + lrow) * LDP + nk * 32 + quad * 8]);
        #pragma unroll
        for (int dt = 0; dt < 8; ++dt) {
            bfrag8 vf[2];
            #pragma unroll
            for (int nk = 0; nk < 2; ++nk)
                vf[nk] = *reinterpret_cast<const bfrag8*>(
                    &Vt[(dt * 16 + lrow) * LDV + nk * 32 + quad * 8]);
            #pragma unroll
            for (int mi = 0; mi < 2; ++mi)
                #pragma unroll
                for (int nk = 0; nk < 2; ++nk)
                    O[mi][dt] = __builtin_amdgcn_mfma_f32_16x16x32_bf16(pf[mi][nk], vf[nk], O[mi][dt], 0, 0, 0);
        }
        __syncthreads();
    }

    #pragma unroll
    for (int mi = 0; mi < 2; ++mi)
        #pragma unroll
        for (int r = 0; r < 4; ++r) {
            float inv = 1.0f / lst[mi][r];
            long q = q0 + wave * 32 + mi * 16 + quad * 4 + r;
            long base = (long)(b * 2048 + q) * 4096 + h * 128 + lrow;
            #pragma unroll
            for (int dt = 0; dt < 8; ++dt)
                y[base + dt * 16] = f2bf(O[mi][dt][r] * inv);
        }
}

// ---------------------------------------------------------------------------
// Workspace layout (224 MB, with aliasing):
//   [0,          100663296)  qkv  : 4096 x 12288 bf16
//   [100663296,  134217728)  xb   : 4096 x 4096 bf16   -> reused as wpt after GEMM1
//   [134217728,  167772160)  (wat part 1) -> y after GEMM1
//   [167772160,  201326592)  (wat part 2) -> vt after GEMM1
//   wat itself: [134217728, 234881024) 12288 x 4096 bf16, dead after GEMM1
// ---------------------------------------------------------------------------
extern "C" void kernel_launch(void* const* d_in, const int* in_sizes, int n_in,
                              void* d_out, int out_size, void* d_ws, size_t ws_size,
                              hipStream_t stream)
{
    const float* x  = (const float*)d_in[0];   // (2,2048,4096) fp32
    const float* wa = (const float*)d_in[1];   // (4096,12288) fp32
    const float* wp = (const float*)d_in[2];   // (4096,4096) fp32
    const float* fc = (const float*)d_in[3];   // (2048,64) fp32
    const float* fs = (const float*)d_in[4];   // (2048,64) fp32
    float* out = (float*)d_out;                // (2,2048,4096) fp32

    char* ws = (char*)d_ws;
    ush* qkv = (ush*)ws;                          // 100.7 MB
    ush* xb  = (ush*)(ws + 100663296);            // 33.5 MB (later wpt)
    ush* wat = (ush*)(ws + 134217728);            // 100.7 MB (later y + vt)
    ush* wpt = xb;                                // aliases xb (dead after GEMM1)
    ush* y   = wat;                               // aliases wat[0:33.5MB)
    ush* vt  = (ush*)(ws + 167772160);            // aliases wat[33.5:67.1MB)

    // 1. x -> bf16
    conv_bf<<<8192, 256, 0, stream>>>(x, xb, 2097152);
    // 2. w_atten (4096x12288) -> wat (12288x4096 bf16, transposed)
    transpose_bf<<<dim3(12288 / 64, 4096 / 64), 256, 0, stream>>>(wa, wat, 4096, 12288);
    // 3. qkv = x @ w_atten   (bf16 x bf16^T -> bf16)
    gemm_bt<ush><<<dim3(12288 / BN, 4096 / BM), 256, 0, stream>>>(xb, wat, qkv, 4096, 12288, 4096);
    // 4. w_proj -> wpt (4096x4096 bf16, transposed); xb is dead now
    transpose_bf<<<dim3(4096 / 64, 4096 / 64), 256, 0, stream>>>(wp, wpt, 4096, 4096);
    // 5. RoPE in-place on q,k
    rope_kernel<<<8388608 / 256, 256, 0, stream>>>(qkv, fc, fs);
    // 6. V -> vt ([bh][d][s] bf16); wat is dead now
    vtrans_kernel<<<dim3(32, 64), 256, 0, stream>>>(qkv, vt);
    // 7. causal flash attention -> y (bf16)
    attn_kernel<<<dim3(64, 16), 256, 0, stream>>>(qkv, vt, y);
    // 8. out = y @ w_proj   (bf16 x bf16^T -> fp32)
    gemm_bt<float><<<dim3(4096 / BN, 4096 / BM), 256, 0, stream>>>(y, wpt, out, 4096, 4096, 4096);
}

// Round 3
// 1107.431 us; speedup vs baseline: 2.9571x; 1.2538x over previous
//
#include <hip/hip_runtime.h>

typedef __bf16 bfrag8 __attribute__((ext_vector_type(8)));
typedef float f32x4 __attribute__((ext_vector_type(4)));
typedef unsigned int u32x4 __attribute__((ext_vector_type(4)));
typedef unsigned short ush;

__device__ __forceinline__ float bf2f(ush s) {
    union { unsigned int u; float f; } un; un.u = ((unsigned int)s) << 16; return un.f;
}
__device__ __forceinline__ ush f2bf(float f) {
    union { float f; unsigned int u; } un; un.f = f;
    unsigned int u = un.u;
    u += 0x7fffu + ((u >> 16) & 1u);   // round-to-nearest-even
    return (ush)(u >> 16);
}

typedef __attribute__((address_space(3))) unsigned int lds_uint;
typedef __attribute__((address_space(1))) const unsigned int glob_uint;

// async 16B/lane global->LDS (dest = wave-uniform base + lane*16)
__device__ __forceinline__ void async_copy16(const ush* g, ush* l) {
    __builtin_amdgcn_global_load_lds((glob_uint*)g, (lds_uint*)l, 16, 0, 0);
}

// ---------------------------------------------------------------------------
// Pre-pass 1: fp32 -> bf16 elementwise (8 elems/thread)
// ---------------------------------------------------------------------------
__global__ __launch_bounds__(256)
void conv_bf(const float* __restrict__ X, ush* __restrict__ Xb, long n8)
{
    long i = (long)blockIdx.x * 256 + threadIdx.x;
    if (i >= n8) return;
    const float4 a = *reinterpret_cast<const float4*>(&X[i * 8]);
    const float4 b = *reinterpret_cast<const float4*>(&X[i * 8 + 4]);
    u32x4 r;
    r[0] = (unsigned int)f2bf(a.x) | ((unsigned int)f2bf(a.y) << 16);
    r[1] = (unsigned int)f2bf(a.z) | ((unsigned int)f2bf(a.w) << 16);
    r[2] = (unsigned int)f2bf(b.x) | ((unsigned int)f2bf(b.y) << 16);
    r[3] = (unsigned int)f2bf(b.z) | ((unsigned int)f2bf(b.w) << 16);
    *reinterpret_cast<u32x4*>(&Xb[i * 8]) = r;
}

// ---------------------------------------------------------------------------
// Pre-pass 2: W (K x N fp32, row-major) -> Wt (N x K bf16, row-major)
// ---------------------------------------------------------------------------
__global__ __launch_bounds__(256)
void transpose_bf(const float* __restrict__ W, ush* __restrict__ Wt, int K, int N)
{
    __shared__ __align__(16) ush T[64][72];
    const int tid = threadIdx.x;
    const long kb = (long)blockIdx.y * 64;
    const long nb = (long)blockIdx.x * 64;

    const int r  = tid >> 4;       // 0..15
    const int c4 = tid & 15;       // col = c4*4
    #pragma unroll
    for (int i = 0; i < 4; ++i) {
        int row = r + i * 16;
        float4 v = *reinterpret_cast<const float4*>(&W[(kb + row) * (long)N + nb + c4 * 4]);
        T[c4 * 4 + 0][row] = f2bf(v.x);
        T[c4 * 4 + 1][row] = f2bf(v.y);
        T[c4 * 4 + 2][row] = f2bf(v.z);
        T[c4 * 4 + 3][row] = f2bf(v.w);
    }
    __syncthreads();

    const int n  = tid >> 3;       // 0..31
    const int kc = tid & 7;        // col = kc*8
    #pragma unroll
    for (int i = 0; i < 2; ++i) {
        int row = n + i * 32;
        *reinterpret_cast<u32x4*>(&Wt[(nb + row) * (long)K + kb + kc * 8]) =
            *reinterpret_cast<const u32x4*>(&T[row][kc * 8]);
    }
}

// ---------------------------------------------------------------------------
// Pre-pass 3: V section of qkv -> vt (bf16 [b*h][d][s]).
// ---------------------------------------------------------------------------
__global__ __launch_bounds__(256)
void vtrans_kernel(const ush* __restrict__ qkv, ush* __restrict__ vt)
{
    __shared__ __align__(16) ush T[128 * 64];
    const int tid = threadIdx.x;
    const int s0 = blockIdx.x * 64;
    const int bh = blockIdx.y;
    const int b = bh >> 5, h = bh & 31;
    const ush* vbase = qkv + (long)b * 2048 * 12288 + 8192 + h * 128;

    #pragma unroll
    for (int i = 0; i < 4; ++i) {
        int c = tid + i * 256;
        int sl = c & 63, cd = c >> 6;        // cd wave-uniform per instruction
        u32x4 v = *reinterpret_cast<const u32x4*>(&vbase[(long)(s0 + sl) * 12288 + cd * 8]);
        const ush* pv = reinterpret_cast<const ush*>(&v);
        #pragma unroll
        for (int j = 0; j < 8; ++j)
            T[(cd * 8 + j) * 64 + sl] = pv[j];
    }
    __syncthreads();

    #pragma unroll
    for (int i = 0; i < 4; ++i) {
        int c = tid + i * 256;
        int d = c >> 3, sc = c & 7;
        *reinterpret_cast<u32x4*>(&vt[((long)bh * 128 + d) * 2048 + s0 + sc * 8]) =
            *reinterpret_cast<const u32x4*>(&T[d * 64 + sc * 8]);
    }
}

// ---------------------------------------------------------------------------
// GEMM, 256x256 8-phase pipelined (T1+T2+T3+T4+T5):
//   C = A(bf16, MxK) * B^T(bf16, NxK row-major)
//   8 waves (2M x 4N), per-wave 128x64; BK=64; 4 phases/K-tile, 16 MFMA each.
//   LDS 128 KiB double-buffered; XOR-swizzled (c16 ^= row&7), source
//   pre-swizzled for linear global_load_lds dest (rule 21).
//   Counted vmcnt(2) at tile boundaries only; loads stay in flight across
//   barriers.  Half-stage schedule (tile u staged at (u-2).4, (u-1).1-3):
//     t.1: A-H1(t+1)   [other slot; its A reads ended (t-1).3]
//     t.2: B-H0(t+1)   [other slot; B reads ended (t-1).4]
//     t.3: B-H1(t+1)
//     t.4: A-H0(t+2)   [CURRENT slot A region; A reads ended t.3]
//   Quadrant order (0,0),(0,1),(1,1),(1,0) makes A LDS-dead after ph3.
// ---------------------------------------------------------------------------
#define GBM 256
#define GBN 256
#define GBK 64

__device__ __forceinline__ void store_out(float* p, float v) { *p = v; }
__device__ __forceinline__ void store_out(ush* p, float v)   { *p = f2bf(v); }

__device__ __forceinline__ bfrag8 lds_frag(const ush* Sb, int row, int c16, int sx) {
    return *reinterpret_cast<const bfrag8*>(&Sb[row * 64 + (((c16) ^ sx) << 3)]);
}

// stage one 128-row half (16 KB) of a 256x64 tile: 2 global_load_lds/thread
__device__ __forceinline__ void stage_half(const ush* __restrict__ G, long row0, long ld,
                                           long kcol, ush* lds_tile, int half,
                                           int wave, int lane)
{
    #pragma unroll
    for (int inst = 0; inst < 2; ++inst) {
        const int base_row = half * 128 + wave * 16 + inst * 8;
        const int r = base_row + (lane >> 3);
        const int c = ((lane & 7) ^ ((lane >> 3) & 7)) << 3;  // inverse swizzle on source
        async_copy16(&G[(row0 + r) * ld + kcol + c], &lds_tile[base_row * 64]);
    }
}

#define LOAD_AF(QM) { _Pragma("unroll") for (int mi = 0; mi < 4; ++mi) \
    _Pragma("unroll") for (int ks = 0; ks < 2; ++ks) \
        af[mi][ks] = lds_frag(SA, wm * 128 + (QM) * 64 + mi * 16 + lrow, ks * 4 + quad, sx); }

#define LOAD_BF(QN) { _Pragma("unroll") for (int ni = 0; ni < 2; ++ni) \
    _Pragma("unroll") for (int ks = 0; ks < 2; ++ks) \
        bf[ni][ks] = lds_frag(SB, wn * 64 + (QN) * 32 + ni * 16 + lrow, ks * 4 + quad, sx); }

#define MFMA_QUAD(QM, QN) { \
    __builtin_amdgcn_s_setprio(1); \
    _Pragma("unroll") for (int mi = 0; mi < 4; ++mi) \
    _Pragma("unroll") for (int ni = 0; ni < 2; ++ni) \
    _Pragma("unroll") for (int ks = 0; ks < 2; ++ks) \
        acc[(QM) * 4 + mi][(QN) * 2 + ni] = __builtin_amdgcn_mfma_f32_16x16x32_bf16( \
            af[mi][ks], bf[ni][ks], acc[(QM) * 4 + mi][(QN) * 2 + ni], 0, 0, 0); \
    __builtin_amdgcn_s_setprio(0); }

template <typename OUT>
__global__ __launch_bounds__(512, 2)
void gemm_bt8(const ush* __restrict__ A, const ush* __restrict__ B,
              OUT* __restrict__ C, int M, int N, int K)
{
    __shared__ __align__(16) ush S[65536];   // 128 KiB: slot p at p*32768 (A), +16384 (B)

    const int tid  = threadIdx.x;
    const int wave = tid >> 6, lane = tid & 63;
    const int wm = wave >> 2, wn = wave & 3;           // 2M x 4N wave grid
    const int lrow = lane & 15, quad = lane >> 4;
    const int sx = lrow & 7;

    // T1: XCD-aware bijective swizzle of the linear block id (nwg % 8 == 0)
    const int gx = gridDim.x;
    const int nwg = gx * gridDim.y;
    int lid = blockIdx.y * gx + blockIdx.x;
    lid = (lid & 7) * (nwg >> 3) + (lid >> 3);
    const long m0 = (long)(lid / gx) * GBM;
    const long n0 = (long)(lid % gx) * GBN;
    const long lK = K;
    const int NT = K / GBK;

    f32x4 acc[8][4];
    const f32x4 fzero = {0.f, 0.f, 0.f, 0.f};
    #pragma unroll
    for (int i = 0; i < 8; ++i)
        #pragma unroll
        for (int j = 0; j < 4; ++j) acc[i][j] = fzero;

    bfrag8 af[4][2], bf[2][2];

    // ---- prologue: tile0 all 4 halves + A-H0(1); allow A-H0(1) in flight ----
    stage_half(A, m0, lK, 0, S,         0, wave, lane);
    stage_half(A, m0, lK, 0, S,         1, wave, lane);
    stage_half(B, n0, lK, 0, S + 16384, 0, wave, lane);
    stage_half(B, n0, lK, 0, S + 16384, 1, wave, lane);
    stage_half(A, m0, lK, GBK, S + 32768, 0, wave, lane);
    asm volatile("s_waitcnt vmcnt(2)" ::: "memory");
    __builtin_amdgcn_s_barrier();

    for (int t = 0; t < NT; ++t) {
        const int p = t & 1;
        ush* SA  = S + p * 32768;
        ush* SB  = SA + 16384;
        ush* SAn = S + (p ^ 1) * 32768;
        ush* SBn = SAn + 16384;
        const long kc1 = (long)(t + 1) * GBK;
        const long kc2 = (long)(t + 2) * GBK;
        const bool st1 = (t + 1) < NT;
        const bool st2 = (t + 2) < NT;

        // phase 1: quadrant (0,0)
        LOAD_AF(0); LOAD_BF(0);
        if (st1) stage_half(A, m0, lK, kc1, SAn, 1, wave, lane);
        __builtin_amdgcn_s_barrier();
        MFMA_QUAD(0, 0);
        __builtin_amdgcn_s_barrier();

        // phase 2: quadrant (0,1)
        LOAD_BF(1);
        if (st1) stage_half(B, n0, lK, kc1, SBn, 0, wave, lane);
        __builtin_amdgcn_s_barrier();
        MFMA_QUAD(0, 1);
        __builtin_amdgcn_s_barrier();

        // phase 3: quadrant (1,1)
        LOAD_AF(1);
        if (st1) stage_half(B, n0, lK, kc1, SBn, 1, wave, lane);
        __builtin_amdgcn_s_barrier();
        MFMA_QUAD(1, 1);
        __builtin_amdgcn_s_barrier();

        // phase 4: quadrant (1,0)  (A region of current slot is now dead)
        LOAD_BF(0);
        if (st2) stage_half(A, m0, lK, kc2, SA, 0, wave, lane);
        __builtin_amdgcn_s_barrier();
        MFMA_QUAD(1, 0);
        __builtin_amdgcn_s_barrier();

        // tile boundary: everything for tile t+1 must have landed; leave only
        // phase-4's A-H0(t+2) loads (2/thread) in flight.
        if (st1) {
            if (st2) asm volatile("s_waitcnt vmcnt(2)" ::: "memory");
            else     asm volatile("s_waitcnt vmcnt(0)" ::: "memory");
            __builtin_amdgcn_s_barrier();
        }
    }

    #pragma unroll
    for (int mi = 0; mi < 8; ++mi)
        #pragma unroll
        for (int ni = 0; ni < 4; ++ni)
            #pragma unroll
            for (int r = 0; r < 4; ++r) {
                long row = m0 + wm * 128 + mi * 16 + quad * 4 + r;
                long col = n0 + wn * 64 + ni * 16 + lrow;
                store_out(&C[row * (long)N + col], acc[mi][ni][r]);
            }
}

// ---------------------------------------------------------------------------
// RoPE in-place on q,k halves of qkv (bf16), fp32 cos/sin tables.
// ---------------------------------------------------------------------------
__global__ void rope_kernel(ush* __restrict__ qkv,
                            const float* __restrict__ cosb, const float* __restrict__ sinb)
{
    int idx = blockIdx.x * 256 + threadIdx.x;  // B*S*H*64 = 8388608
    int i = idx & 63;
    int h = (idx >> 6) & 31;
    int s = (idx >> 11) & 2047;
    int b = idx >> 22;
    float c  = cosb[s * 64 + i];
    float sn = sinb[s * 64 + i];
    long base = ((long)(b * 2048 + s)) * 12288 + h * 128 + 2 * i;
    float qr = bf2f(qkv[base]), qi = bf2f(qkv[base + 1]);
    qkv[base]     = f2bf(qr * c - qi * sn);
    qkv[base + 1] = f2bf(qr * sn + qi * c);
    float kr = bf2f(qkv[base + 4096]), ki = bf2f(qkv[base + 4097]);
    qkv[base + 4096] = f2bf(kr * c - ki * sn);
    qkv[base + 4097] = f2bf(kr * sn + ki * c);
}

// ---------------------------------------------------------------------------
// Flash attention (causal, online softmax), bf16 in/out, fp32 accumulators.
// ---------------------------------------------------------------------------
#define LDK 136
#define LDV 72
#define LDP 72

__global__ __launch_bounds__(256)
void attn_kernel(const ush* __restrict__ qkv, const ush* __restrict__ vt,
                 ush* __restrict__ y)
{
    __shared__ ush Ks[64 * LDK];    // [kv][d]
    __shared__ ush Vt[128 * LDV];   // [d][kv]
    __shared__ ush Ps[128 * LDP];   // [q][kv]

    const int bh = blockIdx.x;
    const int qt = 15 - blockIdx.y;
    const int b = bh >> 5, h = bh & 31;
    const int tid = threadIdx.x, wave = tid >> 6, lane = tid & 63;
    const int lrow = lane & 15, quad = lane >> 4;
    const int q0 = qt * 128;
    const long rs = 12288;
    const ush* qb = qkv + (long)b * 2048 * rs + h * 128;
    const ush* kb = qb + 4096;
    const ush* vtb = vt + (long)bh * 128 * 2048;
    const float scale = 0.08838834764831845f;  // 1/sqrt(128)

    bfrag8 qf[2][4];
    #pragma unroll
    for (int mi = 0; mi < 2; ++mi)
        #pragma unroll
        for (int kk = 0; kk < 4; ++kk) {
            long qrow = q0 + wave * 32 + mi * 16 + lrow;
            qf[mi][kk] = *reinterpret_cast<const bfrag8*>(&qb[qrow * rs + kk * 32 + quad * 8]);
        }

    const f32x4 fzero = {0.f, 0.f, 0.f, 0.f};
    f32x4 O[2][8];
    #pragma unroll
    for (int mi = 0; mi < 2; ++mi)
        #pragma unroll
        for (int dt = 0; dt < 8; ++dt) O[mi][dt] = fzero;
    f32x4 mst[2], lst[2];
    #pragma unroll
    for (int mi = 0; mi < 2; ++mi)
        #pragma unroll
        for (int r = 0; r < 4; ++r) { mst[mi][r] = -1e30f; lst[mi][r] = 0.f; }

    const int ntiles = 2 * qt + 2;
    for (int nt = 0; nt < ntiles; ++nt) {
        const int kv0 = nt * 64;
        #pragma unroll
        for (int i = 0; i < 4; ++i) {
            int c = tid + i * 256;
            int row = c >> 4, cc = c & 15;
            u32x4 v = *reinterpret_cast<const u32x4*>(&kb[(long)(kv0 + row) * rs + cc * 8]);
            *reinterpret_cast<u32x4*>(&Ks[row * LDK + cc * 8]) = v;
        }
        #pragma unroll
        for (int i = 0; i < 4; ++i) {
            int c = tid + i * 256;
            int row = c >> 3, cc = c & 7;
            u32x4 v = *reinterpret_cast<const u32x4*>(&vtb[(long)row * 2048 + kv0 + cc * 8]);
            *reinterpret_cast<u32x4*>(&Vt[row * LDV + cc * 8]) = v;
        }
        __syncthreads();

        f32x4 sv[2][4];
        #pragma unroll
        for (int ni = 0; ni < 4; ++ni) {
            bfrag8 kf[4];
            #pragma unroll
            for (int kk = 0; kk < 4; ++kk)
                kf[kk] = *reinterpret_cast<const bfrag8*>(&Ks[(ni * 16 + lrow) * LDK + kk * 32 + quad * 8]);
            #pragma unroll
            for (int mi = 0; mi < 2; ++mi) {
                f32x4 a = fzero;
                #pragma unroll
                for (int kk = 0; kk < 4; ++kk)
                    a = __builtin_amdgcn_mfma_f32_16x16x32_bf16(qf[mi][kk], kf[kk], a, 0, 0, 0);
                sv[mi][ni] = a;
            }
        }

        #pragma unroll
        for (int mi = 0; mi < 2; ++mi)
            #pragma unroll
            for (int ni = 0; ni < 4; ++ni)
                #pragma unroll
                for (int r = 0; r < 4; ++r) {
                    int q  = q0 + wave * 32 + mi * 16 + quad * 4 + r;
                    int kv = kv0 + ni * 16 + lrow;
                    float x = sv[mi][ni][r] * scale;
                    sv[mi][ni][r] = (kv <= q) ? x : -1e30f;
                }

        #pragma unroll
        for (int mi = 0; mi < 2; ++mi) {
            f32x4 rmax;
            #pragma unroll
            for (int r = 0; r < 4; ++r)
                rmax[r] = fmaxf(fmaxf(sv[mi][0][r], sv[mi][1][r]),
                                fmaxf(sv[mi][2][r], sv[mi][3][r]));
            #pragma unroll
            for (int off = 1; off < 16; off <<= 1)
                #pragma unroll
                for (int r = 0; r < 4; ++r)
                    rmax[r] = fmaxf(rmax[r], __shfl_xor(rmax[r], off, 64));

            f32x4 mnew, alpha;
            #pragma unroll
            for (int r = 0; r < 4; ++r) {
                mnew[r]  = fmaxf(mst[mi][r], rmax[r]);
                alpha[r] = __expf(mst[mi][r] - mnew[r]);
            }
            f32x4 rsum = fzero;
            #pragma unroll
            for (int ni = 0; ni < 4; ++ni)
                #pragma unroll
                for (int r = 0; r < 4; ++r) {
                    float p = __expf(sv[mi][ni][r] - mnew[r]);
                    sv[mi][ni][r] = p;
                    rsum[r] += p;
                }
            #pragma unroll
            for (int off = 1; off < 16; off <<= 1)
                #pragma unroll
                for (int r = 0; r < 4; ++r)
                    rsum[r] += __shfl_xor(rsum[r], off, 64);
            #pragma unroll
            for (int r = 0; r < 4; ++r) {
                lst[mi][r] = lst[mi][r] * alpha[r] + rsum[r];
                mst[mi][r] = mnew[r];
            }
            #pragma unroll
            for (int dt = 0; dt < 8; ++dt)
                #pragma unroll
                for (int r = 0; r < 4; ++r)
                    O[mi][dt][r] *= alpha[r];
            #pragma unroll
            for (int ni = 0; ni < 4; ++ni)
                #pragma unroll
                for (int r = 0; r < 4; ++r)
                    Ps[(wave * 32 + mi * 16 + quad * 4 + r) * LDP + ni * 16 + lrow]
                        = f2bf(sv[mi][ni][r]);
        }

        // no barrier: Ps rows are wave-private

        bfrag8 pf[2][2];
        #pragma unroll
        for (int mi = 0; mi < 2; ++mi)
            #pragma unroll
            for (int nk = 0; nk < 2; ++nk)
                pf[mi][nk] = *reinterpret_cast<const bfrag8*>(
                    &Ps[(wave * 32 + mi * 16 + lrow) * LDP + nk * 32 + quad * 8]);
        #pragma unroll
        for (int dt = 0; dt < 8; ++dt) {
            bfrag8 vf[2];
            #pragma unroll
            for (int nk = 0; nk < 2; ++nk)
                vf[nk] = *reinterpret_cast<const bfrag8*>(
                    &Vt[(dt * 16 + lrow) * LDV + nk * 32 + quad * 8]);
            #pragma unroll
            for (int mi = 0; mi < 2; ++mi)
                #pragma unroll
                for (int nk = 0; nk < 2; ++nk)
                    O[mi][dt] = __builtin_amdgcn_mfma_f32_16x16x32_bf16(pf[mi][nk], vf[nk], O[mi][dt], 0, 0, 0);
        }
        __syncthreads();
    }

    #pragma unroll
    for (int mi = 0; mi < 2; ++mi)
        #pragma unroll
        for (int r = 0; r < 4; ++r) {
            float inv = 1.0f / lst[mi][r];
            long q = q0 + wave * 32 + mi * 16 + quad * 4 + r;
            long base = (long)(b * 2048 + q) * 4096 + h * 128 + lrow;
            #pragma unroll
            for (int dt = 0; dt < 8; ++dt)
                y[base + dt * 16] = f2bf(O[mi][dt][r] * inv);
        }
}

// ---------------------------------------------------------------------------
// Workspace layout (224 MB, with aliasing):
//   [0,          100663296)  qkv  : 4096 x 12288 bf16
//   [100663296,  134217728)  xb   : -> wpt after GEMM1
//   [134217728,  167772160)  y    (aliases dead wat)
//   [167772160,  201326592)  vt   (aliases dead wat)
// ---------------------------------------------------------------------------
extern "C" void kernel_launch(void* const* d_in, const int* in_sizes, int n_in,
                              void* d_out, int out_size, void* d_ws, size_t ws_size,
                              hipStream_t stream)
{
    const float* x  = (const float*)d_in[0];   // (2,2048,4096) fp32
    const float* wa = (const float*)d_in[1];   // (4096,12288) fp32
    const float* wp = (const float*)d_in[2];   // (4096,4096) fp32
    const float* fc = (const float*)d_in[3];   // (2048,64) fp32
    const float* fs = (const float*)d_in[4];   // (2048,64) fp32
    float* out = (float*)d_out;                // (2,2048,4096) fp32

    char* ws = (char*)d_ws;
    ush* qkv = (ush*)ws;                          // 100.7 MB
    ush* xb  = (ush*)(ws + 100663296);            // 33.5 MB (later wpt)
    ush* wat = (ush*)(ws + 134217728);            // 100.7 MB (later y + vt)
    ush* wpt = xb;
    ush* y   = wat;
    ush* vt  = (ush*)(ws + 167772160);

    // 1. x -> bf16
    conv_bf<<<8192, 256, 0, stream>>>(x, xb, 2097152);
    // 2. w_atten (4096x12288) -> wat (12288x4096 bf16, transposed)
    transpose_bf<<<dim3(12288 / 64, 4096 / 64), 256, 0, stream>>>(wa, wat, 4096, 12288);
    // 3. qkv = x @ w_atten   (bf16 x bf16^T -> bf16), 256^2 8-phase
    gemm_bt8<ush><<<dim3(12288 / GBN, 4096 / GBM), 512, 0, stream>>>(xb, wat, qkv, 4096, 12288, 4096);
    // 4. w_proj -> wpt (4096x4096 bf16, transposed); xb dead now
    transpose_bf<<<dim3(4096 / 64, 4096 / 64), 256, 0, stream>>>(wp, wpt, 4096, 4096);
    // 5. RoPE in-place on q,k
    rope_kernel<<<8388608 / 256, 256, 0, stream>>>(qkv, fc, fs);
    // 6. V -> vt ([bh][d][s] bf16); wat dead now
    vtrans_kernel<<<dim3(32, 64), 256, 0, stream>>>(qkv, vt);
    // 7. causal flash attention -> y (bf16)
    attn_kernel<<<dim3(64, 16), 256, 0, stream>>>(qkv, vt, y);
    // 8. out = y @ w_proj   (bf16 x bf16^T -> fp32), 256^2 8-phase
    gemm_bt8<float><<<dim3(4096 / GBN, 4096 / GBM), 512, 0, stream>>>(y, wpt, out, 4096, 4096, 4096);
}

// Round 4
// 1106.419 us; speedup vs baseline: 2.9598x; 1.0009x over previous
//
#include <hip/hip_runtime.h>

typedef __bf16 bfrag8 __attribute__((ext_vector_type(8)));
typedef float f32x4 __attribute__((ext_vector_type(4)));
typedef unsigned int u32x4 __attribute__((ext_vector_type(4)));
typedef unsigned short ush;

__device__ __forceinline__ float bf2f(ush s) {
    union { unsigned int u; float f; } un; un.u = ((unsigned int)s) << 16; return un.f;
}
__device__ __forceinline__ ush f2bf(float f) {
    union { float f; unsigned int u; } un; un.f = f;
    unsigned int u = un.u;
    u += 0x7fffu + ((u >> 16) & 1u);   // round-to-nearest-even
    return (ush)(u >> 16);
}

typedef __attribute__((address_space(3))) unsigned int lds_uint;
typedef __attribute__((address_space(1))) const unsigned int glob_uint;

// async 16B/lane global->LDS (dest = wave-uniform base + lane*16)
__device__ __forceinline__ void async_copy16(const ush* g, ush* l) {
    __builtin_amdgcn_global_load_lds((glob_uint*)g, (lds_uint*)l, 16, 0, 0);
}

// ---------------------------------------------------------------------------
// Pre-pass 1: fp32 -> bf16 elementwise (8 elems/thread)
// ---------------------------------------------------------------------------
__global__ __launch_bounds__(256)
void conv_bf(const float* __restrict__ X, ush* __restrict__ Xb, long n8)
{
    long i = (long)blockIdx.x * 256 + threadIdx.x;
    if (i >= n8) return;
    const float4 a = *reinterpret_cast<const float4*>(&X[i * 8]);
    const float4 b = *reinterpret_cast<const float4*>(&X[i * 8 + 4]);
    u32x4 r;
    r[0] = (unsigned int)f2bf(a.x) | ((unsigned int)f2bf(a.y) << 16);
    r[1] = (unsigned int)f2bf(a.z) | ((unsigned int)f2bf(a.w) << 16);
    r[2] = (unsigned int)f2bf(b.x) | ((unsigned int)f2bf(b.y) << 16);
    r[3] = (unsigned int)f2bf(b.z) | ((unsigned int)f2bf(b.w) << 16);
    *reinterpret_cast<u32x4*>(&Xb[i * 8]) = r;
}

// ---------------------------------------------------------------------------
// Pre-pass 2: W (K x N fp32, row-major) -> Wt (N x K bf16, row-major)
// ---------------------------------------------------------------------------
__global__ __launch_bounds__(256)
void transpose_bf(const float* __restrict__ W, ush* __restrict__ Wt, int K, int N)
{
    __shared__ __align__(16) ush T[64][72];
    const int tid = threadIdx.x;
    const long kb = (long)blockIdx.y * 64;
    const long nb = (long)blockIdx.x * 64;

    const int r  = tid >> 4;       // 0..15
    const int c4 = tid & 15;       // col = c4*4
    #pragma unroll
    for (int i = 0; i < 4; ++i) {
        int row = r + i * 16;
        float4 v = *reinterpret_cast<const float4*>(&W[(kb + row) * (long)N + nb + c4 * 4]);
        T[c4 * 4 + 0][row] = f2bf(v.x);
        T[c4 * 4 + 1][row] = f2bf(v.y);
        T[c4 * 4 + 2][row] = f2bf(v.z);
        T[c4 * 4 + 3][row] = f2bf(v.w);
    }
    __syncthreads();

    const int n  = tid >> 3;       // 0..31
    const int kc = tid & 7;        // col = kc*8
    #pragma unroll
    for (int i = 0; i < 2; ++i) {
        int row = n + i * 32;
        *reinterpret_cast<u32x4*>(&Wt[(nb + row) * (long)K + kb + kc * 8]) =
            *reinterpret_cast<const u32x4*>(&T[row][kc * 8]);
    }
}

// ---------------------------------------------------------------------------
// Pre-pass 3: V section of qkv -> vt (bf16 [b*h][d][s]).
// ---------------------------------------------------------------------------
__global__ __launch_bounds__(256)
void vtrans_kernel(const ush* __restrict__ qkv, ush* __restrict__ vt)
{
    __shared__ __align__(16) ush T[128 * 64];
    const int tid = threadIdx.x;
    const int s0 = blockIdx.x * 64;
    const int bh = blockIdx.y;
    const int b = bh >> 5, h = bh & 31;
    const ush* vbase = qkv + (long)b * 2048 * 12288 + 8192 + h * 128;

    #pragma unroll
    for (int i = 0; i < 4; ++i) {
        int c = tid + i * 256;
        int sl = c & 63, cd = c >> 6;        // cd wave-uniform per instruction
        u32x4 v = *reinterpret_cast<const u32x4*>(&vbase[(long)(s0 + sl) * 12288 + cd * 8]);
        const ush* pv = reinterpret_cast<const ush*>(&v);
        #pragma unroll
        for (int j = 0; j < 8; ++j)
            T[(cd * 8 + j) * 64 + sl] = pv[j];
    }
    __syncthreads();

    #pragma unroll
    for (int i = 0; i < 4; ++i) {
        int c = tid + i * 256;
        int d = c >> 3, sc = c & 7;
        *reinterpret_cast<u32x4*>(&vt[((long)bh * 128 + d) * 2048 + s0 + sc * 8]) =
            *reinterpret_cast<const u32x4*>(&T[d * 64 + sc * 8]);
    }
}

// ---------------------------------------------------------------------------
// GEMM, 256x256 8-phase pipelined (T1-patch + T2 + T3 + T4 + T5):
//   C = A(bf16, MxK) * B^T(bf16, NxK row-major)
//   8 waves (2M x 4N), per-wave 128x64; BK=64; 4 phases/K-tile, 16 MFMA each.
//   LDS 128 KiB double-buffered; XOR-swizzled (c16 ^= row&7), source
//   pre-swizzled for linear global_load_lds dest.
//   Region lifetimes (derived from LOAD_AF/LOAD_BF row coverage):
//     A LDS reads at ph1, ph3 only  -> A(slot) dead after ph3
//     B LDS reads at ph1, ph2, ph4  -> B(slot) dead after ph4
//   Max-depth stage schedule:
//     t.ph1: B(t+1) H0+H1 -> other slot   (cover ~3.5 phases)
//     t.ph4: A(t+2) H0+H1 -> current slot (cover ~5 phases)
//     boundary: vmcnt(4) (only A(t+2)'s 4 loads in flight) + barrier
//   Block mapping: one 2D patch of the block grid per XCD (PH x PW blocks,
//   n-fastest) -> A-tile reused PW consecutive blocks, B shared via L3.
// ---------------------------------------------------------------------------
#define GBM 256
#define GBN 256
#define GBK 64

__device__ __forceinline__ void store_out(float* p, float v) { *p = v; }
__device__ __forceinline__ void store_out(ush* p, float v)   { *p = f2bf(v); }

__device__ __forceinline__ bfrag8 lds_frag(const ush* Sb, int row, int c16, int sx) {
    return *reinterpret_cast<const bfrag8*>(&Sb[row * 64 + (((c16) ^ sx) << 3)]);
}

// stage one 128-row half (16 KB) of a 256x64 tile: 2 global_load_lds/thread
__device__ __forceinline__ void stage_half(const ush* __restrict__ G, long row0, long ld,
                                           long kcol, ush* lds_tile, int half,
                                           int wave, int lane)
{
    #pragma unroll
    for (int inst = 0; inst < 2; ++inst) {
        const int base_row = half * 128 + wave * 16 + inst * 8;
        const int r = base_row + (lane >> 3);
        const int c = ((lane & 7) ^ ((lane >> 3) & 7)) << 3;  // inverse swizzle on source
        async_copy16(&G[(row0 + r) * ld + kcol + c], &lds_tile[base_row * 64]);
    }
}

#define LOAD_AF(QM) { _Pragma("unroll") for (int mi = 0; mi < 4; ++mi) \
    _Pragma("unroll") for (int ks = 0; ks < 2; ++ks) \
        af[mi][ks] = lds_frag(SA, wm * 128 + (QM) * 64 + mi * 16 + lrow, ks * 4 + quad, sx); }

#define LOAD_BF(QN) { _Pragma("unroll") for (int ni = 0; ni < 2; ++ni) \
    _Pragma("unroll") for (int ks = 0; ks < 2; ++ks) \
        bf[ni][ks] = lds_frag(SB, wn * 64 + (QN) * 32 + ni * 16 + lrow, ks * 4 + quad, sx); }

#define MFMA_QUAD(QM, QN) { \
    __builtin_amdgcn_s_setprio(1); \
    _Pragma("unroll") for (int mi = 0; mi < 4; ++mi) \
    _Pragma("unroll") for (int ni = 0; ni < 2; ++ni) \
    _Pragma("unroll") for (int ks = 0; ks < 2; ++ks) \
        acc[(QM) * 4 + mi][(QN) * 2 + ni] = __builtin_amdgcn_mfma_f32_16x16x32_bf16( \
            af[mi][ks], bf[ni][ks], acc[(QM) * 4 + mi][(QN) * 2 + ni], 0, 0, 0); \
    __builtin_amdgcn_s_setprio(0); }

template <typename OUT>
__global__ __launch_bounds__(512, 2)
void gemm_bt8(const ush* __restrict__ A, const ush* __restrict__ B,
              OUT* __restrict__ C, int M, int N, int K, int PH, int PW)
{
    __shared__ __align__(16) ush S[65536];   // 128 KiB: slot p at p*32768 (A), +16384 (B)

    const int tid  = threadIdx.x;
    const int wave = tid >> 6, lane = tid & 63;
    const int wm = wave >> 2, wn = wave & 3;           // 2M x 4N wave grid
    const int lrow = lane & 15, quad = lane >> 4;
    const int sx = lrow & 7;

    // T1-patch: XCD x owns one PH x PW patch of the block grid (requires
    // (gy/PH)*(gx/PW) == 8); n-fastest within patch for A-tile L2 reuse.
    const int gx = gridDim.x;
    const int orig = blockIdx.y * gx + blockIdx.x;   // dispatch order: %8 == XCD
    const int xcd = orig & 7;
    const int q = orig >> 3;                         // sequential-in-time per XCD
    const int pcols = gx / PW;
    const long m0 = (long)((xcd / pcols) * PH + q / PW) * GBM;
    const long n0 = (long)((xcd % pcols) * PW + q % PW) * GBN;
    const long lK = K;
    const int NT = K / GBK;

    f32x4 acc[8][4];
    const f32x4 fzero = {0.f, 0.f, 0.f, 0.f};
    #pragma unroll
    for (int i = 0; i < 8; ++i)
        #pragma unroll
        for (int j = 0; j < 4; ++j) acc[i][j] = fzero;

    bfrag8 af[4][2], bf[2][2];

    // ---- prologue: tile0 (A+B) and A(1); leave A(1)'s 4 loads in flight ----
    stage_half(A, m0, lK, 0,   S,         0, wave, lane);
    stage_half(A, m0, lK, 0,   S,         1, wave, lane);
    stage_half(B, n0, lK, 0,   S + 16384, 0, wave, lane);
    stage_half(B, n0, lK, 0,   S + 16384, 1, wave, lane);
    stage_half(A, m0, lK, GBK, S + 32768, 0, wave, lane);
    stage_half(A, m0, lK, GBK, S + 32768, 1, wave, lane);
    asm volatile("s_waitcnt vmcnt(4)" ::: "memory");
    __builtin_amdgcn_s_barrier();

    for (int t = 0; t < NT; ++t) {
        const int p = t & 1;
        ush* SA  = S + p * 32768;
        ush* SB  = SA + 16384;
        ush* SAn = S + (p ^ 1) * 32768;
        ush* SBn = SAn + 16384;
        const long kc1 = (long)(t + 1) * GBK;
        const long kc2 = (long)(t + 2) * GBK;
        const bool st1 = (t + 1) < NT;
        const bool st2 = (t + 2) < NT;

        // phase 1: quadrant (0,0); stage B(t+1) both halves (other slot's
        // B dead since (t-1).ph4)
        LOAD_AF(0); LOAD_BF(0);
        if (st1) {
            stage_half(B, n0, lK, kc1, SBn, 0, wave, lane);
            stage_half(B, n0, lK, kc1, SBn, 1, wave, lane);
        }
        __builtin_amdgcn_s_barrier();
        MFMA_QUAD(0, 0);
        __builtin_amdgcn_s_barrier();

        // phase 2: quadrant (0,1)
        LOAD_BF(1);
        __builtin_amdgcn_s_barrier();
        MFMA_QUAD(0, 1);
        __builtin_amdgcn_s_barrier();

        // phase 3: quadrant (1,1)  (last A read of current slot)
        LOAD_AF(1);
        __builtin_amdgcn_s_barrier();
        MFMA_QUAD(1, 1);
        __builtin_amdgcn_s_barrier();

        // phase 4: quadrant (1,0); stage A(t+2) both halves into the now-dead
        // A region of the current slot
        LOAD_BF(0);
        if (st2) {
            stage_half(A, m0, lK, kc2, SA, 0, wave, lane);
            stage_half(A, m0, lK, kc2, SA, 1, wave, lane);
        }
        __builtin_amdgcn_s_barrier();
        MFMA_QUAD(1, 0);
        __builtin_amdgcn_s_barrier();

        // tile boundary: A(t+1), B(t+1) must have landed; only A(t+2)'s
        // 4 loads (issued ph4) stay in flight.
        if (st1) {
            if (st2) asm volatile("s_waitcnt vmcnt(4)" ::: "memory");
            else     asm volatile("s_waitcnt vmcnt(0)" ::: "memory");
            __builtin_amdgcn_s_barrier();
        }
    }

    #pragma unroll
    for (int mi = 0; mi < 8; ++mi)
        #pragma unroll
        for (int ni = 0; ni < 4; ++ni)
            #pragma unroll
            for (int r = 0; r < 4; ++r) {
                long row = m0 + wm * 128 + mi * 16 + quad * 4 + r;
                long col = n0 + wn * 64 + ni * 16 + lrow;
                store_out(&C[row * (long)N + col], acc[mi][ni][r]);
            }
}

// ---------------------------------------------------------------------------
// RoPE in-place on q,k halves of qkv (bf16), fp32 cos/sin tables.
// ---------------------------------------------------------------------------
__global__ void rope_kernel(ush* __restrict__ qkv,
                            const float* __restrict__ cosb, const float* __restrict__ sinb)
{
    int idx = blockIdx.x * 256 + threadIdx.x;  // B*S*H*64 = 8388608
    int i = idx & 63;
    int h = (idx >> 6) & 31;
    int s = (idx >> 11) & 2047;
    int b = idx >> 22;
    float c  = cosb[s * 64 + i];
    float sn = sinb[s * 64 + i];
    long base = ((long)(b * 2048 + s)) * 12288 + h * 128 + 2 * i;
    float qr = bf2f(qkv[base]), qi = bf2f(qkv[base + 1]);
    qkv[base]     = f2bf(qr * c - qi * sn);
    qkv[base + 1] = f2bf(qr * sn + qi * c);
    float kr = bf2f(qkv[base + 4096]), ki = bf2f(qkv[base + 4097]);
    qkv[base + 4096] = f2bf(kr * c - ki * sn);
    qkv[base + 4097] = f2bf(kr * sn + ki * c);
}

// ---------------------------------------------------------------------------
// Flash attention (causal, online softmax), bf16 in/out, fp32 accumulators.
// ---------------------------------------------------------------------------
#define LDK 136
#define LDV 72
#define LDP 72

__global__ __launch_bounds__(256)
void attn_kernel(const ush* __restrict__ qkv, const ush* __restrict__ vt,
                 ush* __restrict__ y)
{
    __shared__ ush Ks[64 * LDK];    // [kv][d]
    __shared__ ush Vt[128 * LDV];   // [d][kv]
    __shared__ ush Ps[128 * LDP];   // [q][kv]

    const int bh = blockIdx.x;
    const int qt = 15 - blockIdx.y;
    const int b = bh >> 5, h = bh & 31;
    const int tid = threadIdx.x, wave = tid >> 6, lane = tid & 63;
    const int lrow = lane & 15, quad = lane >> 4;
    const int q0 = qt * 128;
    const long rs = 12288;
    const ush* qb = qkv + (long)b * 2048 * rs + h * 128;
    const ush* kb = qb + 4096;
    const ush* vtb = vt + (long)bh * 128 * 2048;
    const float scale = 0.08838834764831845f;  // 1/sqrt(128)

    bfrag8 qf[2][4];
    #pragma unroll
    for (int mi = 0; mi < 2; ++mi)
        #pragma unroll
        for (int kk = 0; kk < 4; ++kk) {
            long qrow = q0 + wave * 32 + mi * 16 + lrow;
            qf[mi][kk] = *reinterpret_cast<const bfrag8*>(&qb[qrow * rs + kk * 32 + quad * 8]);
        }

    const f32x4 fzero = {0.f, 0.f, 0.f, 0.f};
    f32x4 O[2][8];
    #pragma unroll
    for (int mi = 0; mi < 2; ++mi)
        #pragma unroll
        for (int dt = 0; dt < 8; ++dt) O[mi][dt] = fzero;
    f32x4 mst[2], lst[2];
    #pragma unroll
    for (int mi = 0; mi < 2; ++mi)
        #pragma unroll
        for (int r = 0; r < 4; ++r) { mst[mi][r] = -1e30f; lst[mi][r] = 0.f; }

    const int ntiles = 2 * qt + 2;
    for (int nt = 0; nt < ntiles; ++nt) {
        const int kv0 = nt * 64;
        #pragma unroll
        for (int i = 0; i < 4; ++i) {
            int c = tid + i * 256;
            int row = c >> 4, cc = c & 15;
            u32x4 v = *reinterpret_cast<const u32x4*>(&kb[(long)(kv0 + row) * rs + cc * 8]);
            *reinterpret_cast<u32x4*>(&Ks[row * LDK + cc * 8]) = v;
        }
        #pragma unroll
        for (int i = 0; i < 4; ++i) {
            int c = tid + i * 256;
            int row = c >> 3, cc = c & 7;
            u32x4 v = *reinterpret_cast<const u32x4*>(&vtb[(long)row * 2048 + kv0 + cc * 8]);
            *reinterpret_cast<u32x4*>(&Vt[row * LDV + cc * 8]) = v;
        }
        __syncthreads();

        f32x4 sv[2][4];
        #pragma unroll
        for (int ni = 0; ni < 4; ++ni) {
            bfrag8 kf[4];
            #pragma unroll
            for (int kk = 0; kk < 4; ++kk)
                kf[kk] = *reinterpret_cast<const bfrag8*>(&Ks[(ni * 16 + lrow) * LDK + kk * 32 + quad * 8]);
            #pragma unroll
            for (int mi = 0; mi < 2; ++mi) {
                f32x4 a = fzero;
                #pragma unroll
                for (int kk = 0; kk < 4; ++kk)
                    a = __builtin_amdgcn_mfma_f32_16x16x32_bf16(qf[mi][kk], kf[kk], a, 0, 0, 0);
                sv[mi][ni] = a;
            }
        }

        #pragma unroll
        for (int mi = 0; mi < 2; ++mi)
            #pragma unroll
            for (int ni = 0; ni < 4; ++ni)
                #pragma unroll
                for (int r = 0; r < 4; ++r) {
                    int q  = q0 + wave * 32 + mi * 16 + quad * 4 + r;
                    int kv = kv0 + ni * 16 + lrow;
                    float x = sv[mi][ni][r] * scale;
                    sv[mi][ni][r] = (kv <= q) ? x : -1e30f;
                }

        #pragma unroll
        for (int mi = 0; mi < 2; ++mi) {
            f32x4 rmax;
            #pragma unroll
            for (int r = 0; r < 4; ++r)
                rmax[r] = fmaxf(fmaxf(sv[mi][0][r], sv[mi][1][r]),
                                fmaxf(sv[mi][2][r], sv[mi][3][r]));
            #pragma unroll
            for (int off = 1; off < 16; off <<= 1)
                #pragma unroll
                for (int r = 0; r < 4; ++r)
                    rmax[r] = fmaxf(rmax[r], __shfl_xor(rmax[r], off, 64));

            f32x4 mnew, alpha;
            #pragma unroll
            for (int r = 0; r < 4; ++r) {
                mnew[r]  = fmaxf(mst[mi][r], rmax[r]);
                alpha[r] = __expf(mst[mi][r] - mnew[r]);
            }
            f32x4 rsum = fzero;
            #pragma unroll
            for (int ni = 0; ni < 4; ++ni)
                #pragma unroll
                for (int r = 0; r < 4; ++r) {
                    float p = __expf(sv[mi][ni][r] - mnew[r]);
                    sv[mi][ni][r] = p;
                    rsum[r] += p;
                }
            #pragma unroll
            for (int off = 1; off < 16; off <<= 1)
                #pragma unroll
                for (int r = 0; r < 4; ++r)
                    rsum[r] += __shfl_xor(rsum[r], off, 64);
            #pragma unroll
            for (int r = 0; r < 4; ++r) {
                lst[mi][r] = lst[mi][r] * alpha[r] + rsum[r];
                mst[mi][r] = mnew[r];
            }
            #pragma unroll
            for (int dt = 0; dt < 8; ++dt)
                #pragma unroll
                for (int r = 0; r < 4; ++r)
                    O[mi][dt][r] *= alpha[r];
            #pragma unroll
            for (int ni = 0; ni < 4; ++ni)
                #pragma unroll
                for (int r = 0; r < 4; ++r)
                    Ps[(wave * 32 + mi * 16 + quad * 4 + r) * LDP + ni * 16 + lrow]
                        = f2bf(sv[mi][ni][r]);
        }

        // no barrier: Ps rows are wave-private

        bfrag8 pf[2][2];
        #pragma unroll
        for (int mi = 0; mi < 2; ++mi)
            #pragma unroll
            for (int nk = 0; nk < 2; ++nk)
                pf[mi][nk] = *reinterpret_cast<const bfrag8*>(
                    &Ps[(wave * 32 + mi * 16 + lrow) * LDP + nk * 32 + quad * 8]);
        #pragma unroll
        for (int dt = 0; dt < 8; ++dt) {
            bfrag8 vf[2];
            #pragma unroll
            for (int nk = 0; nk < 2; ++nk)
                vf[nk] = *reinterpret_cast<const bfrag8*>(
                    &Vt[(dt * 16 + lrow) * LDV + nk * 32 + quad * 8]);
            #pragma unroll
            for (int mi = 0; mi < 2; ++mi)
                #pragma unroll
                for (int nk = 0; nk < 2; ++nk)
                    O[mi][dt] = __builtin_amdgcn_mfma_f32_16x16x32_bf16(pf[mi][nk], vf[nk], O[mi][dt], 0, 0, 0);
        }
        __syncthreads();
    }

    #pragma unroll
    for (int mi = 0; mi < 2; ++mi)
        #pragma unroll
        for (int r = 0; r < 4; ++r) {
            float inv = 1.0f / lst[mi][r];
            long q = q0 + wave * 32 + mi * 16 + quad * 4 + r;
            long base = (long)(b * 2048 + q) * 4096 + h * 128 + lrow;
            #pragma unroll
            for (int dt = 0; dt < 8; ++dt)
                y[base + dt * 16] = f2bf(O[mi][dt][r] * inv);
        }
}

// ---------------------------------------------------------------------------
// Workspace layout (224 MB, with aliasing):
//   [0,          100663296)  qkv  : 4096 x 12288 bf16
//   [100663296,  134217728)  xb   : -> wpt after GEMM1
//   [134217728,  167772160)  y    (aliases dead wat)
//   [167772160,  201326592)  vt   (aliases dead wat)
// ---------------------------------------------------------------------------
extern "C" void kernel_launch(void* const* d_in, const int* in_sizes, int n_in,
                              void* d_out, int out_size, void* d_ws, size_t ws_size,
                              hipStream_t stream)
{
    const float* x  = (const float*)d_in[0];   // (2,2048,4096) fp32
    const float* wa = (const float*)d_in[1];   // (4096,12288) fp32
    const float* wp = (const float*)d_in[2];   // (4096,4096) fp32
    const float* fc = (const float*)d_in[3];   // (2048,64) fp32
    const float* fs = (const float*)d_in[4];   // (2048,64) fp32
    float* out = (float*)d_out;                // (2,2048,4096) fp32

    char* ws = (char*)d_ws;
    ush* qkv = (ush*)ws;                          // 100.7 MB
    ush* xb  = (ush*)(ws + 100663296);            // 33.5 MB (later wpt)
    ush* wat = (ush*)(ws + 134217728);            // 100.7 MB (later y + vt)
    ush* wpt = xb;
    ush* y   = wat;
    ush* vt  = (ush*)(ws + 167772160);

    // 1. x -> bf16
    conv_bf<<<8192, 256, 0, stream>>>(x, xb, 2097152);
    // 2. w_atten (4096x12288) -> wat (12288x4096 bf16, transposed)
    transpose_bf<<<dim3(12288 / 64, 4096 / 64), 256, 0, stream>>>(wa, wat, 4096, 12288);
    // 3. qkv = x @ w_atten  (grid 48x16 blocks; patches 8Mx12N per XCD)
    gemm_bt8<ush><<<dim3(12288 / GBN, 4096 / GBM), 512, 0, stream>>>(xb, wat, qkv, 4096, 12288, 4096, 8, 12);
    // 4. w_proj -> wpt (4096x4096 bf16, transposed); xb dead now
    transpose_bf<<<dim3(4096 / 64, 4096 / 64), 256, 0, stream>>>(wp, wpt, 4096, 4096);
    // 5. RoPE in-place on q,k
    rope_kernel<<<8388608 / 256, 256, 0, stream>>>(qkv, fc, fs);
    // 6. V -> vt ([bh][d][s] bf16); wat dead now
    vtrans_kernel<<<dim3(32, 64), 256, 0, stream>>>(qkv, vt);
    // 7. causal flash attention -> y (bf16)
    attn_kernel<<<dim3(64, 16), 256, 0, stream>>>(qkv, vt, y);
    // 8. out = y @ w_proj  (grid 16x16 blocks; patches 4Mx8N per XCD)
    gemm_bt8<float><<<dim3(4096 / GBN, 4096 / GBM), 512, 0, stream>>>(y, wpt, out, 4096, 4096, 4096, 4, 8);
}